// Round 9
// baseline (2081.187 us; speedup 1.0000x reference)
//
#include <hip/hip_runtime.h>
#include <math.h>

// Problem constants (fixed by reference):
//   x: (8,12,512,256) fp32 -> tokens T = 8*12*512 = 49152, D = 256
//   DEPTH=6, HEADS=4, DH=64, N(seq)=512, batch-rows BL=96
#define T_TOK 49152
#define DMODEL 256
#define NSEQ 512
#define BLROWS 96
#define LOG2E 1.4426950408889634f

typedef unsigned short ushortT;
using frag_ab = __attribute__((ext_vector_type(8))) short;   // 8 bf16
using f32x4   = __attribute__((ext_vector_type(4))) float;   // 4 fp32 acc

__device__ __forceinline__ ushortT f2b(float f) {
    union { float f; unsigned int u; } v; v.f = f;
    unsigned int u = v.u;
    u += 0x7FFFu + ((u >> 16) & 1u);   // RNE
    return (ushortT)(u >> 16);
}
__device__ __forceinline__ float b2f(ushortT h) {
    union { unsigned int u; float f; } v; v.u = ((unsigned int)h) << 16;
    return v.f;
}

#if __has_builtin(__builtin_amdgcn_exp2f)
#define FEXP2(x) __builtin_amdgcn_exp2f(x)
#else
#define FEXP2(x) __expf((x) * 0.6931471805599453f)
#endif

// pack two f32 -> one dword of 2 bf16 (RNE) in a single VALU op
__device__ __forceinline__ unsigned int cvtpk_bf16(float lo, float hi) {
    unsigned int r;
    asm("v_cvt_pk_bf16_f32 %0, %1, %2" : "=v"(r) : "v"(lo), "v"(hi));
    return r;
}

// async global->LDS DMA, 16 B per lane; LDS dest = wave-uniform base + lane*16
__device__ __forceinline__ void gload_lds16(const ushortT* g, ushortT* l) {
    __builtin_amdgcn_global_load_lds(
        (const __attribute__((address_space(1))) unsigned int*)g,
        (__attribute__((address_space(3))) unsigned int*)l, 16, 0, 0);
}

// ---------------------------------------------------------------------------
// Weight prep (once per launch): fp32 W[K][N] -> bf16 tiles [nb][ks][n:128][k:64]
// contiguous 8192-ushort tiles, ordered tt = nb*KS + ks.
// Layer bases (ushorts): qkv d*196608 | proj 1179648+d*65536 |
//                        w1 1572864+d*262144 | w2 3145728+d*262144 ; end 4718592
// ---------------------------------------------------------------------------
__global__ __launch_bounds__(256) void wprep_kernel(const float* __restrict__ qkv_w,
                                                    const float* __restrict__ proj_w,
                                                    const float* __restrict__ w1,
                                                    const float* __restrict__ w2,
                                                    ushortT* __restrict__ out) {
    __shared__ float Ls[64][132];
    int bid = blockIdx.x;
    int d = bid / 96, t = bid % 96;
    const float* src; int N, KS; size_t dbase; int tt;
    if (t < 24)      { src = qkv_w  + (size_t)d * 256 * 768;  N = 768;  KS = 4;  dbase = (size_t)d * 196608;            tt = t;      }
    else if (t < 32) { src = proj_w + (size_t)d * 256 * 256;  N = 256;  KS = 4;  dbase = 1179648 + (size_t)d * 65536;   tt = t - 24; }
    else if (t < 64) { src = w1     + (size_t)d * 256 * 1024; N = 1024; KS = 4;  dbase = 1572864 + (size_t)d * 262144;  tt = t - 32; }
    else             { src = w2     + (size_t)d * 1024 * 256; N = 256;  KS = 16; dbase = 3145728 + (size_t)d * 262144;  tt = t - 64; }
    int nb = tt / KS, ks = tt % KS;
    int k0 = ks * 64, n0 = nb * 128;
    int tid = threadIdx.x;
#pragma unroll
    for (int i = 0; i < 8; ++i) {
        int fidx = tid + i * 256;            // 0..2047 float4s of the 64x128 tile
        int kk = fidx >> 5, ng = fidx & 31;
        float4 v = *(const float4*)(src + (size_t)(k0 + kk) * N + n0 + ng * 4);
        *(float4*)&Ls[kk][ng * 4] = v;
    }
    __syncthreads();
    int n = tid & 127, kh = tid >> 7;
    ushortT* dst = out + dbase + (size_t)tt * 8192 + n * 64 + kh * 32;
    ushortT tmp[32];
#pragma unroll
    for (int j = 0; j < 32; ++j) tmp[j] = f2b(Ls[kh * 32 + j][n]);
#pragma unroll
    for (int u = 0; u < 4; ++u) *(uint4*)(dst + u * 8) = *(uint4*)(tmp + u * 8);
}

// ---------------------------------------------------------------------------
// LayerNorm: one wave per 256-float row. OB: bf16 out (for GEMM A), else fp32.
// ---------------------------------------------------------------------------
template <bool OB>
__global__ __launch_bounds__(256) void ln_kernel(const float* __restrict__ in,
                                                 void* __restrict__ out,
                                                 const float* __restrict__ s,
                                                 const float* __restrict__ b) {
    int wave = threadIdx.x >> 6;
    int lane = threadIdx.x & 63;
    size_t row = (size_t)blockIdx.x * 4 + wave;
    float4 v = reinterpret_cast<const float4*>(in + row * DMODEL)[lane];
    float sum = v.x + v.y + v.z + v.w;
    float ssq = v.x * v.x + v.y * v.y + v.z * v.z + v.w * v.w;
#pragma unroll
    for (int m = 1; m <= 32; m <<= 1) {
        sum += __shfl_xor(sum, m, 64);
        ssq += __shfl_xor(ssq, m, 64);
    }
    float mean = sum * (1.0f / 256.0f);
    float var = ssq * (1.0f / 256.0f) - mean * mean;
    float rstd = rsqrtf(var + 1e-5f);
    float4 sv = reinterpret_cast<const float4*>(s)[lane];
    float4 bv = reinterpret_cast<const float4*>(b)[lane];
    float o0 = (v.x - mean) * rstd * sv.x + bv.x;
    float o1 = (v.y - mean) * rstd * sv.y + bv.y;
    float o2 = (v.z - mean) * rstd * sv.z + bv.z;
    float o3 = (v.w - mean) * rstd * sv.w + bv.w;
    if (OB) {
        ushortT* po = (ushortT*)out + row * DMODEL + lane * 4;
        ushort4 ov; ov.x = f2b(o0); ov.y = f2b(o1); ov.z = f2b(o2); ov.w = f2b(o3);
        *(ushort4*)po = ov;
    } else {
        float4 ov; ov.x = o0; ov.y = o1; ov.z = o2; ov.w = o3;
        reinterpret_cast<float4*>((float*)out + row * DMODEL)[lane] = ov;
    }
}

// ---------------------------------------------------------------------------
// bf16 MFMA GEMM: C[M x N] = A[M x K](bf16) @ W(tiled bf16) + bias.
// 128x128 tile, BK=64, 4 waves (2x2), 4x4 16x16x32 frags per wave.
// K-loop: double-buffered LDS, staged via global_load_lds (16 B/lane DMA),
// ONE barrier per K-step; STAGE(t+1) issues before compute(t).
// Swizzle: LDS dest linear; XOR applied on the per-lane GLOBAL source column
// (unit ^= row&7) and on reads (rule #21).
// Epilogue routes C through LDS so global stores are uint4/float4
// row-contiguous (256 B per 16 lanes).
// EPI: 0 bias -> bf16 | 1 bias+gelu -> bf16 | 2 bias+residual(in-place f32 R)
// ---------------------------------------------------------------------------
template <int EPI>
__global__ __launch_bounds__(256) void gemm_bf16(const ushortT* __restrict__ A,
                                                 const ushortT* __restrict__ Wt,
                                                 const float* __restrict__ bias,
                                                 float* __restrict__ R,
                                                 ushortT* __restrict__ Cb,
                                                 int K, int N) {
    __shared__ ushortT smem[32768];      // 2 x (A 8192 | B 8192), reused as C-stage
    const int nb = blockIdx.x, n0 = nb * 128;
    const int m0 = blockIdx.y * 128;
    const int tid = threadIdx.x, lane = tid & 63, wave = tid >> 6;
    const int wr = wave >> 1, wc = wave & 1;
    const int KS = K >> 6;
    const size_t wtile = (size_t)nb * KS * 8192;

    const int rA = lane >> 3;                 // 0..7 (row within 8-row DMA group)
    const int colsw = (lane & 7) ^ rA;        // pre-swizzled source 16B unit

    // stage K-step kt into buffer buf; each wave: 4x A-DMA + 4x B-DMA (1 KB each)
    auto STAGE = [&](int buf, int kt) {
        ushortT* Ad = smem + buf * 16384;
        ushortT* Bd = Ad + 8192;
#pragma unroll
        for (int c2 = 0; c2 < 4; ++c2) {
            int rb = wave * 32 + c2 * 8;      // LDS row base (wave-uniform)
            int row = rb + rA;                // per-lane row
            gload_lds16(A + (size_t)(m0 + row) * K + kt * 64 + colsw * 8,
                        Ad + rb * 64);
            gload_lds16(Wt + wtile + (size_t)kt * 8192 + row * 64 + colsw * 8,
                        Bd + rb * 64);
        }
    };

    f32x4 acc[4][4];
#pragma unroll
    for (int i = 0; i < 4; ++i)
#pragma unroll
        for (int j = 0; j < 4; ++j) acc[i][j] = (f32x4)0.0f;

    STAGE(0, 0);
    __syncthreads();                          // drains vmcnt -> buf0 ready
    int cur = 0;
    for (int kt = 0; kt < KS; ++kt) {
        if (kt + 1 < KS) STAGE(cur ^ 1, kt + 1);   // DMA flies under MFMAs
        const ushortT* Ab = smem + cur * 16384;
        const ushortT* Bb = Ab + 8192;
#pragma unroll
        for (int kst = 0; kst < 2; ++kst) {
            frag_ab af[4], bf4[4];
            int ku = kst * 4 + (lane >> 4);
#pragma unroll
            for (int f = 0; f < 4; ++f) {
                int row = wr * 64 + f * 16 + (lane & 15);
                af[f] = *(const frag_ab*)&Ab[row * 64 + ((ku ^ (row & 7)) << 3)];
                int col = wc * 64 + f * 16 + (lane & 15);
                bf4[f] = *(const frag_ab*)&Bb[col * 64 + ((ku ^ (col & 7)) << 3)];
            }
#pragma unroll
            for (int mf = 0; mf < 4; ++mf)
#pragma unroll
                for (int nf = 0; nf < 4; ++nf)
                    acc[mf][nf] = __builtin_amdgcn_mfma_f32_16x16x32_bf16(
                        af[mf], bf4[nf], acc[mf][nf], 0, 0, 0);
        }
        __syncthreads();   // drains this step's DMA; protects buf reuse
        cur ^= 1;
    }

    // ---- epilogue via LDS transpose -> wide coalesced stores ----
    const int cg = lane >> 4, cl = lane & 15;
    if (EPI != 2) {
        ushortT* Cs = smem;   // [128][128] bf16, 16B-unit row-XOR swizzle
#pragma unroll
        for (int nf = 0; nf < 4; ++nf) {
            int col = wc * 64 + nf * 16 + cl;
            float bv = bias[n0 + col];
#pragma unroll
            for (int mf = 0; mf < 4; ++mf)
#pragma unroll
                for (int r = 0; r < 4; ++r) {
                    int row = wr * 64 + mf * 16 + cg * 4 + r;
                    float c = acc[mf][nf][r] + bv;
                    if (EPI == 1) {
                        // gelu(tanh) == x * sigmoid(1.5957691*(x+0.044715x^3))
                        c = c / (1.0f + __expf(-1.5957691216f * (c + 0.044715f * c * c * c)));
                    }
                    Cs[row * 128 + (((col >> 3) ^ (row & 7)) << 3) + (col & 7)] = f2b(c);
                }
        }
        __syncthreads();
#pragma unroll
        for (int it = 0; it < 8; ++it) {
            int idx = tid + it * 256;
            int row = idx >> 4, u = idx & 15;          // 16 lanes = 1 full row
            uint4 v = *(uint4*)&Cs[row * 128 + ((u ^ (row & 7)) << 3)];
            *(uint4*)&Cb[(size_t)(m0 + row) * N + n0 + u * 8] = v;
        }
    } else {
        float* Cf = (float*)smem;   // [64][128] fp32, float4-unit row-XOR swizzle
#pragma unroll
        for (int h = 0; h < 2; ++h) {
            if (wr == h) {
#pragma unroll
                for (int nf = 0; nf < 4; ++nf) {
                    int col = wc * 64 + nf * 16 + cl;
                    float bv = bias[n0 + col];
#pragma unroll
                    for (int mf = 0; mf < 4; ++mf)
#pragma unroll
                        for (int r = 0; r < 4; ++r) {
                            int rl = mf * 16 + cg * 4 + r;
                            Cf[rl * 128 + (((col >> 2) ^ (rl & 7)) << 2) + (col & 3)] =
                                acc[mf][nf][r] + bv;
                        }
                }
            }
            __syncthreads();
#pragma unroll
            for (int it = 0; it < 8; ++it) {
                int idx = tid + it * 256;
                int row2 = idx >> 5, u = idx & 31;     // 32 lanes = 1 full row
                float4 c4 = *(float4*)&Cf[row2 * 128 + ((u ^ (row2 & 7)) << 2)];
                float* rp = R + (size_t)(m0 + h * 64 + row2) * N + n0 + u * 4;
                float4 r4 = *(float4*)rp;
                r4.x += c4.x; r4.y += c4.y; r4.z += c4.z; r4.w += c4.w;
                *(float4*)rp = r4;
            }
            if (h == 0) __syncthreads();
        }
    }
}

// ---------------------------------------------------------------------------
// MFMA flash attention, QBLK=128, 8 waves, DOUBLE-BUFFERED K/V + async stage.
// Per 64-key tile: K staged via global_load_lds DMA into Ks[buf] (linear dest,
// XOR on per-lane global source col — rule #21); V reg-loaded at loop top and
// transpose-scattered into Vt[buf] AFTER softmax (T14 issue-early/write-late);
// ONE barrier per tile. S = QK^T (8 MFMA, setprio); online softmax in exp2
// domain with defer-max (THR=11.5 ~ e^8); P via v_cvt_pk_bf16_f32 into
// wave-private Ps rows; O += P@V (8 MFMA, setprio).
// LDS: Ks 2x8K + Vt 2x9K + Ps 16K + rl 4K = 54 KB.
// ---------------------------------------------------------------------------
__global__ __launch_bounds__(512) void attn_kernel(const ushortT* __restrict__ qkv,
                                                   const float* __restrict__ rel,
                                                   ushortT* __restrict__ o) {
    __shared__ ushortT Ks[2][64 * 64];   // [j][d] swizzled: unit ^= (j&7)
    __shared__ ushortT Vt[2][64 * 72];   // [d][j] transposed: j ^= ((d>>3)<<3)
    __shared__ ushortT Ps[128 * 64];     // [i][j] swizzled like Ks (wave-private)
    __shared__ float   rl[1024];         // rel-pos bias * log2e for this head

    const int pair = blockIdx.x, qb = blockIdx.y;
    const int bl = pair >> 2, hh = pair & 3;
    const int tid = threadIdx.x;
    const int lane = tid & 63, w = tid >> 6;       // w = 0..7
    const int c15 = lane & 15, g = lane >> 4;
    const size_t base = (size_t)bl * NSEQ * 768;
    const int qoff = hh * 64, koff = 256 + hh * 64, voff = 512 + hh * 64;
    const int i0 = qb * 128;

    for (int i = tid; i < 1023; i += 512) rl[i] = rel[(size_t)i * 4 + hh] * LOG2E;

    // staging roles: 512 threads cover 64 keys x 8 d-groups
    const int sj = tid >> 3, sdg = tid & 7;
    const ushortT* kvb = qkv + base;
    // K DMA: wave-uniform LDS base + lane*16B == &Ks[buf][sj*64 + sdg*8]
    auto KSTAGE = [&](int buf, int kt) {
        gload_lds16(kvb + (size_t)(kt * 64 + sj) * 768 + koff + ((sdg ^ (sj & 7)) << 3),
                    &Ks[buf][0] + (size_t)w * 512);
    };
    uint4 vreg;
    auto VLOAD = [&](int kt) {
        vreg = *(const uint4*)(kvb + (size_t)(kt * 64 + sj) * 768 + voff + sdg * 8);
    };
    auto VWRITE = [&](int buf) {
        ushortT tmp[8];
        *(uint4*)tmp = vreg;
        int jc = sj ^ (sdg << 3);
#pragma unroll
        for (int e = 0; e < 8; ++e) Vt[buf][(sdg * 8 + e) * 72 + jc] = tmp[e];
    };

    // Q fragments: lane holds Q[i0 + w*16 + c15][kst*32 + g*8 + jj]
    frag_ab qf[2];
    {
        const ushortT* qp = kvb + (size_t)(i0 + w * 16 + c15) * 768 + qoff + g * 8;
        qf[0] = *(const frag_ab*)(qp);
        qf[1] = *(const frag_ab*)(qp + 32);
    }

    float m_i[4], l_i[4];
    f32x4 oacc[4];
#pragma unroll
    for (int r = 0; r < 4; ++r) { m_i[r] = -1e30f; l_i[r] = 0.0f; }
#pragma unroll
    for (int nf = 0; nf < 4; ++nf) oacc[nf] = (f32x4)0.0f;

    const int irow = w * 16 + g * 4;          // C-layout row base (block-local)

    // prologue: stage tile 0
    VLOAD(0);
    KSTAGE(0, 0);
    VWRITE(0);
    __syncthreads();                          // drains K-DMA + V writes

    int cur = 0;
    for (int kt = 0; kt < 8; ++kt) {
        // prefetch tile kt+1: K-DMA flies + V regs load under QK^T/softmax
        if (kt < 7) { KSTAGE(cur ^ 1, kt + 1); VLOAD(kt + 1); }

        // ---- S = Q @ K^T (8 MFMA) ----
        f32x4 sacc[4];
#pragma unroll
        for (int nf = 0; nf < 4; ++nf) sacc[nf] = (f32x4)0.0f;
        __builtin_amdgcn_s_setprio(1);
#pragma unroll
        for (int kst = 0; kst < 2; ++kst) {
            int ku = kst * 4 + g;
#pragma unroll
            for (int nf = 0; nf < 4; ++nf) {
                int j = nf * 16 + c15;
                frag_ab kf = *(frag_ab*)&Ks[cur][j * 64 + ((ku ^ (j & 7)) << 3)];
                sacc[nf] = __builtin_amdgcn_mfma_f32_16x16x32_bf16(qf[kst], kf, sacc[nf], 0, 0, 0);
            }
        }
        __builtin_amdgcn_s_setprio(0);

        // ---- online softmax, exp2 domain (row = irow + r, col = nf*16+c15) ----
        float sv[4][4];     // [nf][r]
        const int rlb = i0 + irow - kt * 64 - c15 + 511;
#pragma unroll
        for (int nf = 0; nf < 4; ++nf)
#pragma unroll
            for (int r = 0; r < 4; ++r)
                sv[nf][r] = sacc[nf][r] * (0.125f * LOG2E) + rl[rlb + r - nf * 16];

        float rmax[4];
#pragma unroll
        for (int r = 0; r < 4; ++r) {
            float rm = fmaxf(fmaxf(sv[0][r], sv[1][r]), fmaxf(sv[2][r], sv[3][r]));
#pragma unroll
            for (int m = 1; m <= 8; m <<= 1) rm = fmaxf(rm, __shfl_xor(rm, m, 64));
            rmax[r] = rm;
        }
        // defer-max: skip rescale while max growth stays under 2^11.5 (~e^8)
        bool cskip = true;
#pragma unroll
        for (int r = 0; r < 4; ++r) cskip = cskip && (rmax[r] <= m_i[r] + 11.5f);
        if (!__all(cskip)) {
#pragma unroll
            for (int r = 0; r < 4; ++r) {
                float mn = fmaxf(m_i[r], rmax[r]);
                float cr = FEXP2(m_i[r] - mn);
                m_i[r] = mn;
                l_i[r] *= cr;
#pragma unroll
                for (int nf = 0; nf < 4; ++nf) oacc[nf][r] *= cr;
            }
        }

        float psum[4] = {0.0f, 0.0f, 0.0f, 0.0f};
        unsigned int words[4][4];
#pragma unroll
        for (int nf = 0; nf < 4; ++nf)
#pragma unroll
            for (int r = 0; r < 4; ++r) {
                float p = FEXP2(sv[nf][r] - m_i[r]);
                psum[r] += p;
                float po = __shfl_xor(p, 1, 64);
                words[nf][r] = cvtpk_bf16(p, po);   // (own, neighbor) bf16 pair
            }
#pragma unroll
        for (int r = 0; r < 4; ++r) {
#pragma unroll
            for (int m = 1; m <= 8; m <<= 1) psum[r] += __shfl_xor(psum[r], m, 64);
            l_i[r] += psum[r];
        }

        // write prefetched V into the other buffer (hidden HBM latency spent)
        if (kt < 7) VWRITE(cur ^ 1);

        // P store: even lanes write (p[j2], p[j2+1]) words, wave-private rows
        if (!(lane & 1)) {
#pragma unroll
            for (int nf = 0; nf < 4; ++nf) {
                int j2 = nf * 16 + c15;
#pragma unroll
                for (int r = 0; r < 4; ++r) {
                    int i = irow + r;
                    *(unsigned int*)&Ps[i * 64 + ((((j2 >> 3) ^ (i & 7))) << 3) + (j2 & 7)] =
                        words[nf][r];
                }
            }
        }

        // ---- O += P @ V (8 MFMA); P rows are wave-private (no barrier) ----
        __builtin_amdgcn_s_setprio(1);
#pragma unroll
        for (int ks2 = 0; ks2 < 2; ++ks2) {
            int ip = w * 16 + c15;
            int jb = ks2 * 32 + g * 8;
            frag_ab pf = *(frag_ab*)&Ps[ip * 64 + (((jb >> 3) ^ (ip & 7)) << 3)];
#pragma unroll
            for (int nf = 0; nf < 4; ++nf) {
                int dh = nf * 16 + c15;
                int jv = jb ^ ((dh >> 3) << 3);
                frag_ab vf = *(frag_ab*)&Vt[cur][dh * 72 + jv];
                oacc[nf] = __builtin_amdgcn_mfma_f32_16x16x32_bf16(pf, vf, oacc[nf], 0, 0, 0);
            }
        }
        __builtin_amdgcn_s_setprio(0);

        __syncthreads();   // next tile's K-DMA/V-writes complete; cur readers done
        cur ^= 1;
    }

    // epilogue: O /= l, pack pairs via cvt_pk, even lanes write words
    float inv[4];
#pragma unroll
    for (int r = 0; r < 4; ++r) inv[r] = 1.0f / l_i[r];
#pragma unroll
    for (int nf = 0; nf < 4; ++nf)
#pragma unroll
        for (int r = 0; r < 4; ++r) {
            float own = oacc[nf][r] * inv[r];
            float other = __shfl_xor(own, 1, 64);
            if (!(lane & 1)) {
                size_t trow = (size_t)bl * NSEQ + i0 + irow + r;
                *(unsigned int*)&o[trow * DMODEL + hh * 64 + nf * 16 + c15] =
                    cvtpk_bf16(own, other);
            }
        }
}

// ---------------------------------------------------------------------------
// Orchestration. h (residual, fp32) lives in d_out. ws layout:
//   [0, 4718592) ushorts : pre-tiled bf16 weights (9.44 MB)
//   then per-chunk scratch (bf16): xnC TCx256 | big TCx1024 (qkv 768 / mid) |
//   oC TCx256  -> TC*3072 bytes. NC chosen from ws_size only (capture-stable).
// ---------------------------------------------------------------------------
extern "C" void kernel_launch(void* const* d_in, const int* in_sizes, int n_in,
                              void* d_out, int out_size, void* d_ws, size_t ws_size,
                              hipStream_t stream) {
    const float* x       = (const float*)d_in[0];
    const float* ln1_s   = (const float*)d_in[1];
    const float* ln1_b   = (const float*)d_in[2];
    const float* qkv_w   = (const float*)d_in[3];
    const float* qkv_b   = (const float*)d_in[4];
    const float* proj_w  = (const float*)d_in[5];
    const float* proj_b  = (const float*)d_in[6];
    const float* rel_tab = (const float*)d_in[7];
    const float* ln2_s   = (const float*)d_in[8];
    const float* ln2_b   = (const float*)d_in[9];
    const float* w1      = (const float*)d_in[10];
    const float* b1      = (const float*)d_in[11];
    const float* w2      = (const float*)d_in[12];
    const float* b2      = (const float*)d_in[13];
    const float* lnf_s   = (const float*)d_in[14];
    const float* lnf_b   = (const float*)d_in[15];

    float* h = (float*)d_out;
    ushortT* wsu = (ushortT*)d_ws;
    const size_t WPRE = 4718592;  // ushorts of tiled weights

    static const int cands[12] = {1, 2, 3, 4, 6, 8, 12, 16, 24, 32, 48, 96};
    int NC = 96;
    for (int i = 0; i < 12; ++i) {
        size_t tc = (size_t)T_TOK / cands[i];
        if (WPRE * 2 + tc * 3072 <= ws_size) { NC = cands[i]; break; }
    }
    const int TC = T_TOK / NC;
    const int BLC = BLROWS / NC;
    ushortT* xnC = wsu + WPRE;
    ushortT* big = xnC + (size_t)TC * 256;
    ushortT* oC  = big + (size_t)TC * 1024;

    wprep_kernel<<<576, 256, 0, stream>>>(qkv_w, proj_w, w1, w2, wsu);
    hipMemcpyAsync(h, x, (size_t)T_TOK * DMODEL * sizeof(float),
                   hipMemcpyDeviceToDevice, stream);

    dim3 blk(256);
    for (int d = 0; d < 6; ++d) {
        for (int c = 0; c < NC; ++c) {
            float* hc = h + (size_t)c * TC * DMODEL;
            ln_kernel<true><<<TC / 4, blk, 0, stream>>>(hc, xnC, ln1_s + d * 256, ln1_b + d * 256);
            gemm_bf16<0><<<dim3(6, TC / 128), blk, 0, stream>>>(
                xnC, wsu + (size_t)d * 196608, qkv_b + d * 768, nullptr, big, 256, 768);
            attn_kernel<<<dim3(BLC * 4, NSEQ / 128), 512, 0, stream>>>(
                big, rel_tab + (size_t)d * 1023 * 4, oC);
            gemm_bf16<2><<<dim3(2, TC / 128), blk, 0, stream>>>(
                oC, wsu + 1179648 + (size_t)d * 65536, proj_b + d * 256, hc, nullptr, 256, 256);
        }
        for (int c = 0; c < NC; ++c) {
            float* hc = h + (size_t)c * TC * DMODEL;
            ln_kernel<true><<<TC / 4, blk, 0, stream>>>(hc, xnC, ln2_s + d * 256, ln2_b + d * 256);
            gemm_bf16<1><<<dim3(8, TC / 128), blk, 0, stream>>>(
                xnC, wsu + 1572864 + (size_t)d * 262144, b1 + d * 1024, nullptr, big, 256, 1024);
            gemm_bf16<2><<<dim3(2, TC / 128), blk, 0, stream>>>(
                big, wsu + 3145728 + (size_t)d * 262144, b2 + d * 256, hc, nullptr, 1024, 256);
        }
    }
    ln_kernel<false><<<T_TOK / 4, blk, 0, stream>>>(h, h, lnf_s, lnf_b);
}

// Round 10
// 1845.513 us; speedup vs baseline: 1.1277x; 1.1277x over previous
//
#include <hip/hip_runtime.h>
#include <math.h>

// Problem constants (fixed by reference):
//   x: (8,12,512,256) fp32 -> tokens T = 8*12*512 = 49152, D = 256
//   DEPTH=6, HEADS=4, DH=64, N(seq)=512, batch-rows BL=96
#define T_TOK 49152
#define DMODEL 256
#define NSEQ 512
#define BLROWS 96
#define LOG2E 1.4426950408889634f

typedef unsigned short ushortT;
using frag_ab = __attribute__((ext_vector_type(8))) short;   // 8 bf16
using f32x4   = __attribute__((ext_vector_type(4))) float;   // 4 fp32 acc

__device__ __forceinline__ ushortT f2b(float f) {
    union { float f; unsigned int u; } v; v.f = f;
    unsigned int u = v.u;
    u += 0x7FFFu + ((u >> 16) & 1u);   // RNE
    return (ushortT)(u >> 16);
}
__device__ __forceinline__ float b2f(ushortT h) {
    union { unsigned int u; float f; } v; v.u = ((unsigned int)h) << 16;
    return v.f;
}

#if __has_builtin(__builtin_amdgcn_exp2f)
#define FEXP2(x) __builtin_amdgcn_exp2f(x)
#else
#define FEXP2(x) __expf((x) * 0.6931471805599453f)
#endif

// pack two f32 -> one dword of 2 bf16 (RNE) in a single VALU op
__device__ __forceinline__ unsigned int cvtpk_bf16(float lo, float hi) {
    unsigned int r;
    asm("v_cvt_pk_bf16_f32 %0, %1, %2" : "=v"(r) : "v"(lo), "v"(hi));
    return r;
}

// max over the 16-lane DPP row via row_ror rotations (VALU pipe, no LDS)
__device__ __forceinline__ float rowmax16(float x) {
    union { float f; int i; } u, v;
    u.f = x;
    v.i = __builtin_amdgcn_update_dpp(0, u.i, 0x121, 0xf, 0xf, true);  // ror:1
    x = fmaxf(x, v.f); u.f = x;
    v.i = __builtin_amdgcn_update_dpp(0, u.i, 0x122, 0xf, 0xf, true);  // ror:2
    x = fmaxf(x, v.f); u.f = x;
    v.i = __builtin_amdgcn_update_dpp(0, u.i, 0x124, 0xf, 0xf, true);  // ror:4
    x = fmaxf(x, v.f); u.f = x;
    v.i = __builtin_amdgcn_update_dpp(0, u.i, 0x128, 0xf, 0xf, true);  // ror:8
    x = fmaxf(x, v.f);
    return x;
}

// async global->LDS DMA, 16 B per lane; LDS dest = wave-uniform base + lane*16
__device__ __forceinline__ void gload_lds16(const ushortT* g, ushortT* l) {
    __builtin_amdgcn_global_load_lds(
        (const __attribute__((address_space(1))) unsigned int*)g,
        (__attribute__((address_space(3))) unsigned int*)l, 16, 0, 0);
}

// ---------------------------------------------------------------------------
// Weight prep (once per launch): fp32 W[K][N] -> bf16 tiles [nb][ks][n:128][k:64]
// contiguous 8192-ushort tiles, ordered tt = nb*KS + ks.
// Layer bases (ushorts): qkv d*196608 | proj 1179648+d*65536 |
//                        w1 1572864+d*262144 | w2 3145728+d*262144 ; end 4718592
// ---------------------------------------------------------------------------
__global__ __launch_bounds__(256) void wprep_kernel(const float* __restrict__ qkv_w,
                                                    const float* __restrict__ proj_w,
                                                    const float* __restrict__ w1,
                                                    const float* __restrict__ w2,
                                                    ushortT* __restrict__ out) {
    __shared__ float Ls[64][132];
    int bid = blockIdx.x;
    int d = bid / 96, t = bid % 96;
    const float* src; int N, KS; size_t dbase; int tt;
    if (t < 24)      { src = qkv_w  + (size_t)d * 256 * 768;  N = 768;  KS = 4;  dbase = (size_t)d * 196608;            tt = t;      }
    else if (t < 32) { src = proj_w + (size_t)d * 256 * 256;  N = 256;  KS = 4;  dbase = 1179648 + (size_t)d * 65536;   tt = t - 24; }
    else if (t < 64) { src = w1     + (size_t)d * 256 * 1024; N = 1024; KS = 4;  dbase = 1572864 + (size_t)d * 262144;  tt = t - 32; }
    else             { src = w2     + (size_t)d * 1024 * 256; N = 256;  KS = 16; dbase = 3145728 + (size_t)d * 262144;  tt = t - 64; }
    int nb = tt / KS, ks = tt % KS;
    int k0 = ks * 64, n0 = nb * 128;
    int tid = threadIdx.x;
#pragma unroll
    for (int i = 0; i < 8; ++i) {
        int fidx = tid + i * 256;            // 0..2047 float4s of the 64x128 tile
        int kk = fidx >> 5, ng = fidx & 31;
        float4 v = *(const float4*)(src + (size_t)(k0 + kk) * N + n0 + ng * 4);
        *(float4*)&Ls[kk][ng * 4] = v;
    }
    __syncthreads();
    int n = tid & 127, kh = tid >> 7;
    ushortT* dst = out + dbase + (size_t)tt * 8192 + n * 64 + kh * 32;
    ushortT tmp[32];
#pragma unroll
    for (int j = 0; j < 32; ++j) tmp[j] = f2b(Ls[kh * 32 + j][n]);
#pragma unroll
    for (int u = 0; u < 4; ++u) *(uint4*)(dst + u * 8) = *(uint4*)(tmp + u * 8);
}

// ---------------------------------------------------------------------------
// LayerNorm: one wave per 256-float row. OB: bf16 out (for GEMM A), else fp32.
// ---------------------------------------------------------------------------
template <bool OB>
__global__ __launch_bounds__(256) void ln_kernel(const float* __restrict__ in,
                                                 void* __restrict__ out,
                                                 const float* __restrict__ s,
                                                 const float* __restrict__ b) {
    int wave = threadIdx.x >> 6;
    int lane = threadIdx.x & 63;
    size_t row = (size_t)blockIdx.x * 4 + wave;
    float4 v = reinterpret_cast<const float4*>(in + row * DMODEL)[lane];
    float sum = v.x + v.y + v.z + v.w;
    float ssq = v.x * v.x + v.y * v.y + v.z * v.z + v.w * v.w;
#pragma unroll
    for (int m = 1; m <= 32; m <<= 1) {
        sum += __shfl_xor(sum, m, 64);
        ssq += __shfl_xor(ssq, m, 64);
    }
    float mean = sum * (1.0f / 256.0f);
    float var = ssq * (1.0f / 256.0f) - mean * mean;
    float rstd = rsqrtf(var + 1e-5f);
    float4 sv = reinterpret_cast<const float4*>(s)[lane];
    float4 bv = reinterpret_cast<const float4*>(b)[lane];
    float o0 = (v.x - mean) * rstd * sv.x + bv.x;
    float o1 = (v.y - mean) * rstd * sv.y + bv.y;
    float o2 = (v.z - mean) * rstd * sv.z + bv.z;
    float o3 = (v.w - mean) * rstd * sv.w + bv.w;
    if (OB) {
        ushortT* po = (ushortT*)out + row * DMODEL + lane * 4;
        ushort4 ov; ov.x = f2b(o0); ov.y = f2b(o1); ov.z = f2b(o2); ov.w = f2b(o3);
        *(ushort4*)po = ov;
    } else {
        float4 ov; ov.x = o0; ov.y = o1; ov.z = o2; ov.w = o3;
        reinterpret_cast<float4*>((float*)out + row * DMODEL)[lane] = ov;
    }
}

// ---------------------------------------------------------------------------
// bf16 MFMA GEMM: C[M x N] = A[M x K](bf16) @ W(tiled bf16) + bias.
// 128x128 tile, BK=64, 4 waves (2x2), 4x4 16x16x32 frags per wave.
// K-loop: double-buffered LDS, staged via global_load_lds (16 B/lane DMA),
// ONE barrier per K-step; STAGE(t+1) issues before compute(t).
// Swizzle: LDS dest linear; XOR applied on the per-lane GLOBAL source column
// (unit ^= row&7) and on reads (rule #21).
// Epilogue routes C through LDS so global stores are uint4/float4
// row-contiguous (256 B per 16 lanes).
// EPI: 0 bias -> bf16 | 1 bias+gelu -> bf16 | 2 bias+residual(in-place f32 R)
// ---------------------------------------------------------------------------
template <int EPI>
__global__ __launch_bounds__(256) void gemm_bf16(const ushortT* __restrict__ A,
                                                 const ushortT* __restrict__ Wt,
                                                 const float* __restrict__ bias,
                                                 float* __restrict__ R,
                                                 ushortT* __restrict__ Cb,
                                                 int K, int N) {
    __shared__ ushortT smem[32768];      // 2 x (A 8192 | B 8192), reused as C-stage
    const int nb = blockIdx.x, n0 = nb * 128;
    const int m0 = blockIdx.y * 128;
    const int tid = threadIdx.x, lane = tid & 63, wave = tid >> 6;
    const int wr = wave >> 1, wc = wave & 1;
    const int KS = K >> 6;
    const size_t wtile = (size_t)nb * KS * 8192;

    const int rA = lane >> 3;                 // 0..7 (row within 8-row DMA group)
    const int colsw = (lane & 7) ^ rA;        // pre-swizzled source 16B unit

    // stage K-step kt into buffer buf; each wave: 4x A-DMA + 4x B-DMA (1 KB each)
    auto STAGE = [&](int buf, int kt) {
        ushortT* Ad = smem + buf * 16384;
        ushortT* Bd = Ad + 8192;
#pragma unroll
        for (int c2 = 0; c2 < 4; ++c2) {
            int rb = wave * 32 + c2 * 8;      // LDS row base (wave-uniform)
            int row = rb + rA;                // per-lane row
            gload_lds16(A + (size_t)(m0 + row) * K + kt * 64 + colsw * 8,
                        Ad + rb * 64);
            gload_lds16(Wt + wtile + (size_t)kt * 8192 + row * 64 + colsw * 8,
                        Bd + rb * 64);
        }
    };

    f32x4 acc[4][4];
#pragma unroll
    for (int i = 0; i < 4; ++i)
#pragma unroll
        for (int j = 0; j < 4; ++j) acc[i][j] = (f32x4)0.0f;

    STAGE(0, 0);
    __syncthreads();                          // drains vmcnt -> buf0 ready
    int cur = 0;
    for (int kt = 0; kt < KS; ++kt) {
        if (kt + 1 < KS) STAGE(cur ^ 1, kt + 1);   // DMA flies under MFMAs
        const ushortT* Ab = smem + cur * 16384;
        const ushortT* Bb = Ab + 8192;
#pragma unroll
        for (int kst = 0; kst < 2; ++kst) {
            frag_ab af[4], bf4[4];
            int ku = kst * 4 + (lane >> 4);
#pragma unroll
            for (int f = 0; f < 4; ++f) {
                int row = wr * 64 + f * 16 + (lane & 15);
                af[f] = *(const frag_ab*)&Ab[row * 64 + ((ku ^ (row & 7)) << 3)];
                int col = wc * 64 + f * 16 + (lane & 15);
                bf4[f] = *(const frag_ab*)&Bb[col * 64 + ((ku ^ (col & 7)) << 3)];
            }
#pragma unroll
            for (int mf = 0; mf < 4; ++mf)
#pragma unroll
                for (int nf = 0; nf < 4; ++nf)
                    acc[mf][nf] = __builtin_amdgcn_mfma_f32_16x16x32_bf16(
                        af[mf], bf4[nf], acc[mf][nf], 0, 0, 0);
        }
        __syncthreads();   // drains this step's DMA; protects buf reuse
        cur ^= 1;
    }

    // ---- epilogue via LDS transpose -> wide coalesced stores ----
    const int cg = lane >> 4, cl = lane & 15;
    if (EPI != 2) {
        ushortT* Cs = smem;   // [128][128] bf16, 16B-unit row-XOR swizzle
#pragma unroll
        for (int nf = 0; nf < 4; ++nf) {
            int col = wc * 64 + nf * 16 + cl;
            float bv = bias[n0 + col];
#pragma unroll
            for (int mf = 0; mf < 4; ++mf)
#pragma unroll
                for (int r = 0; r < 4; ++r) {
                    int row = wr * 64 + mf * 16 + cg * 4 + r;
                    float c = acc[mf][nf][r] + bv;
                    if (EPI == 1) {
                        // gelu(tanh) == x * sigmoid(1.5957691*(x+0.044715x^3))
                        c = c / (1.0f + __expf(-1.5957691216f * (c + 0.044715f * c * c * c)));
                    }
                    Cs[row * 128 + (((col >> 3) ^ (row & 7)) << 3) + (col & 7)] = f2b(c);
                }
        }
        __syncthreads();
#pragma unroll
        for (int it = 0; it < 8; ++it) {
            int idx = tid + it * 256;
            int row = idx >> 4, u = idx & 15;          // 16 lanes = 1 full row
            uint4 v = *(uint4*)&Cs[row * 128 + ((u ^ (row & 7)) << 3)];
            *(uint4*)&Cb[(size_t)(m0 + row) * N + n0 + u * 8] = v;
        }
    } else {
        float* Cf = (float*)smem;   // [64][128] fp32, float4-unit row-XOR swizzle
#pragma unroll
        for (int h = 0; h < 2; ++h) {
            if (wr == h) {
#pragma unroll
                for (int nf = 0; nf < 4; ++nf) {
                    int col = wc * 64 + nf * 16 + cl;
                    float bv = bias[n0 + col];
#pragma unroll
                    for (int mf = 0; mf < 4; ++mf)
#pragma unroll
                        for (int r = 0; r < 4; ++r) {
                            int rl = mf * 16 + cg * 4 + r;
                            Cf[rl * 128 + (((col >> 2) ^ (rl & 7)) << 2) + (col & 3)] =
                                acc[mf][nf][r] + bv;
                        }
                }
            }
            __syncthreads();
#pragma unroll
            for (int it = 0; it < 8; ++it) {
                int idx = tid + it * 256;
                int row2 = idx >> 5, u = idx & 31;     // 32 lanes = 1 full row
                float4 c4 = *(float4*)&Cf[row2 * 128 + ((u ^ (row2 & 7)) << 2)];
                float* rp = R + (size_t)(m0 + h * 64 + row2) * N + n0 + u * 4;
                float4 r4 = *(float4*)rp;
                r4.x += c4.x; r4.y += c4.y; r4.z += c4.z; r4.w += c4.w;
                *(float4*)rp = r4;
            }
            if (h == 0) __syncthreads();
        }
    }
}

// ---------------------------------------------------------------------------
// MFMA flash attention, QBLK=128, 8 waves, double-buffered K/V + async stage.
// DS-pipe diet (round 10): (1) row-sum l accumulated via MFMA with an all-ones
// B fragment (lacc, same C-layout/rescale as oacc) -> no psum shuffles;
// (2) rmax reduced with DPP row_ror rotations (VALU pipe, no ds_swizzle);
// (3) P stored as per-lane ds_write_b16 (cvt_pk low half) -> no neighbor
// shuffles. Online softmax stays exact for any m (defer-max THR bounds P).
// ---------------------------------------------------------------------------
__global__ __launch_bounds__(512) void attn_kernel(const ushortT* __restrict__ qkv,
                                                   const float* __restrict__ rel,
                                                   ushortT* __restrict__ o) {
    __shared__ ushortT Ks[2][64 * 64];   // [j][d] swizzled: unit ^= (j&7)
    __shared__ ushortT Vt[2][64 * 72];   // [d][j] transposed: j ^= ((d>>3)<<3)
    __shared__ ushortT Ps[128 * 64];     // [i][j] swizzled like Ks (wave-private)
    __shared__ float   rl[1024];         // rel-pos bias * log2e for this head

    const int pair = blockIdx.x, qb = blockIdx.y;
    const int bl = pair >> 2, hh = pair & 3;
    const int tid = threadIdx.x;
    const int lane = tid & 63, w = tid >> 6;       // w = 0..7
    const int c15 = lane & 15, g = lane >> 4;
    const size_t base = (size_t)bl * NSEQ * 768;
    const int qoff = hh * 64, koff = 256 + hh * 64, voff = 512 + hh * 64;
    const int i0 = qb * 128;

    for (int i = tid; i < 1023; i += 512) rl[i] = rel[(size_t)i * 4 + hh] * LOG2E;

    // staging roles: 512 threads cover 64 keys x 8 d-groups
    const int sj = tid >> 3, sdg = tid & 7;
    const ushortT* kvb = qkv + base;
    // K DMA: wave-uniform LDS base + lane*16B == &Ks[buf][sj*64 + sdg*8]
    auto KSTAGE = [&](int buf, int kt) {
        gload_lds16(kvb + (size_t)(kt * 64 + sj) * 768 + koff + ((sdg ^ (sj & 7)) << 3),
                    &Ks[buf][0] + (size_t)w * 512);
    };
    uint4 vreg;
    auto VLOAD = [&](int kt) {
        vreg = *(const uint4*)(kvb + (size_t)(kt * 64 + sj) * 768 + voff + sdg * 8);
    };
    auto VWRITE = [&](int buf) {
        ushortT tmp[8];
        *(uint4*)tmp = vreg;
        int jc = sj ^ (sdg << 3);
#pragma unroll
        for (int e = 0; e < 8; ++e) Vt[buf][(sdg * 8 + e) * 72 + jc] = tmp[e];
    };

    // Q fragments: lane holds Q[i0 + w*16 + c15][kst*32 + g*8 + jj]
    frag_ab qf[2];
    {
        const ushortT* qp = kvb + (size_t)(i0 + w * 16 + c15) * 768 + qoff + g * 8;
        qf[0] = *(const frag_ab*)(qp);
        qf[1] = *(const frag_ab*)(qp + 32);
    }

    // all-ones bf16 B fragment for the row-sum MFMA (1.0bf16 = 0x3F80)
    frag_ab ones1;
#pragma unroll
    for (int e = 0; e < 8; ++e) ones1[e] = (short)0x3F80;

    float m_i[4];
    f32x4 oacc[4], lacc;
#pragma unroll
    for (int r = 0; r < 4; ++r) m_i[r] = -1e30f;
#pragma unroll
    for (int nf = 0; nf < 4; ++nf) oacc[nf] = (f32x4)0.0f;
    lacc = (f32x4)0.0f;

    const int irow = w * 16 + g * 4;          // C-layout row base (block-local)

    // prologue: stage tile 0
    VLOAD(0);
    KSTAGE(0, 0);
    VWRITE(0);
    __syncthreads();                          // drains K-DMA + V writes

    int cur = 0;
    for (int kt = 0; kt < 8; ++kt) {
        // prefetch tile kt+1: K-DMA flies + V regs load under QK^T/softmax
        if (kt < 7) { KSTAGE(cur ^ 1, kt + 1); VLOAD(kt + 1); }

        // ---- S = Q @ K^T (8 MFMA) ----
        f32x4 sacc[4];
#pragma unroll
        for (int nf = 0; nf < 4; ++nf) sacc[nf] = (f32x4)0.0f;
        __builtin_amdgcn_s_setprio(1);
#pragma unroll
        for (int kst = 0; kst < 2; ++kst) {
            int ku = kst * 4 + g;
#pragma unroll
            for (int nf = 0; nf < 4; ++nf) {
                int j = nf * 16 + c15;
                frag_ab kf = *(frag_ab*)&Ks[cur][j * 64 + ((ku ^ (j & 7)) << 3)];
                sacc[nf] = __builtin_amdgcn_mfma_f32_16x16x32_bf16(qf[kst], kf, sacc[nf], 0, 0, 0);
            }
        }
        __builtin_amdgcn_s_setprio(0);

        // ---- online softmax, exp2 domain (row = irow + r, col = nf*16+c15) ----
        float sv[4][4];     // [nf][r]
        const int rlb = i0 + irow - kt * 64 - c15 + 511;
#pragma unroll
        for (int nf = 0; nf < 4; ++nf)
#pragma unroll
            for (int r = 0; r < 4; ++r)
                sv[nf][r] = sacc[nf][r] * (0.125f * LOG2E) + rl[rlb + r - nf * 16];

        float rmax[4];
#pragma unroll
        for (int r = 0; r < 4; ++r)
            rmax[r] = rowmax16(fmaxf(fmaxf(sv[0][r], sv[1][r]), fmaxf(sv[2][r], sv[3][r])));

        // defer-max: skip rescale while max growth stays under 2^11.5 (~e^8)
        bool cskip = true;
#pragma unroll
        for (int r = 0; r < 4; ++r) cskip = cskip && (rmax[r] <= m_i[r] + 11.5f);
        if (!__all(cskip)) {
#pragma unroll
            for (int r = 0; r < 4; ++r) {
                float mn = fmaxf(m_i[r], rmax[r]);
                float cr = FEXP2(m_i[r] - mn);
                m_i[r] = mn;
                lacc[r] *= cr;
#pragma unroll
                for (int nf = 0; nf < 4; ++nf) oacc[nf][r] *= cr;
            }
        }

        // P = exp2(sv - m), per-lane bf16 store (no neighbor exchange)
#pragma unroll
        for (int nf = 0; nf < 4; ++nf) {
            int j2 = nf * 16 + c15;
#pragma unroll
            for (int r = 0; r < 4; ++r) {
                float p = FEXP2(sv[nf][r] - m_i[r]);
                unsigned int pw = cvtpk_bf16(p, p);   // low word = bf16(p)
                int i = irow + r;
                Ps[i * 64 + (((j2 >> 3) ^ (i & 7)) << 3) + (j2 & 7)] = (ushortT)pw;
            }
        }

        // write prefetched V into the other buffer (hidden HBM latency spent)
        if (kt < 7) VWRITE(cur ^ 1);

        // ---- O += P @ V, l += P @ 1 (10 MFMA); P rows wave-private ----
        __builtin_amdgcn_s_setprio(1);
#pragma unroll
        for (int ks2 = 0; ks2 < 2; ++ks2) {
            int ip = w * 16 + c15;
            int jb = ks2 * 32 + g * 8;
            frag_ab pf = *(frag_ab*)&Ps[ip * 64 + (((jb >> 3) ^ (ip & 7)) << 3)];
            lacc = __builtin_amdgcn_mfma_f32_16x16x32_bf16(pf, ones1, lacc, 0, 0, 0);
#pragma unroll
            for (int nf = 0; nf < 4; ++nf) {
                int dh = nf * 16 + c15;
                int jv = jb ^ ((dh >> 3) << 3);
                frag_ab vf = *(frag_ab*)&Vt[cur][dh * 72 + jv];
                oacc[nf] = __builtin_amdgcn_mfma_f32_16x16x32_bf16(pf, vf, oacc[nf], 0, 0, 0);
            }
        }
        __builtin_amdgcn_s_setprio(0);

        __syncthreads();   // next tile's K-DMA/V-writes complete; cur readers done
        cur ^= 1;
    }

    // epilogue: O /= l (l from the ones-MFMA), pack pairs, even lanes write
    float inv[4];
#pragma unroll
    for (int r = 0; r < 4; ++r) inv[r] = 1.0f / lacc[r];
#pragma unroll
    for (int nf = 0; nf < 4; ++nf)
#pragma unroll
        for (int r = 0; r < 4; ++r) {
            float own = oacc[nf][r] * inv[r];
            float other = __shfl_xor(own, 1, 64);
            if (!(lane & 1)) {
                size_t trow = (size_t)bl * NSEQ + i0 + irow + r;
                *(unsigned int*)&o[trow * DMODEL + hh * 64 + nf * 16 + c15] =
                    cvtpk_bf16(own, other);
            }
        }
}

// ---------------------------------------------------------------------------
// Orchestration. h (residual, fp32) lives in d_out. ws layout:
//   [0, 4718592) ushorts : pre-tiled bf16 weights (9.44 MB)
//   then per-chunk scratch (bf16): xnC TCx256 | big TCx1024 (qkv 768 / mid) |
//   oC TCx256  -> TC*3072 bytes. NC chosen from ws_size only (capture-stable).
// ---------------------------------------------------------------------------
extern "C" void kernel_launch(void* const* d_in, const int* in_sizes, int n_in,
                              void* d_out, int out_size, void* d_ws, size_t ws_size,
                              hipStream_t stream) {
    const float* x       = (const float*)d_in[0];
    const float* ln1_s   = (const float*)d_in[1];
    const float* ln1_b   = (const float*)d_in[2];
    const float* qkv_w   = (const float*)d_in[3];
    const float* qkv_b   = (const float*)d_in[4];
    const float* proj_w  = (const float*)d_in[5];
    const float* proj_b  = (const float*)d_in[6];
    const float* rel_tab = (const float*)d_in[7];
    const float* ln2_s   = (const float*)d_in[8];
    const float* ln2_b   = (const float*)d_in[9];
    const float* w1      = (const float*)d_in[10];
    const float* b1      = (const float*)d_in[11];
    const float* w2      = (const float*)d_in[12];
    const float* b2      = (const float*)d_in[13];
    const float* lnf_s   = (const float*)d_in[14];
    const float* lnf_b   = (const float*)d_in[15];

    float* h = (float*)d_out;
    ushortT* wsu = (ushortT*)d_ws;
    const size_t WPRE = 4718592;  // ushorts of tiled weights

    static const int cands[12] = {1, 2, 3, 4, 6, 8, 12, 16, 24, 32, 48, 96};
    int NC = 96;
    for (int i = 0; i < 12; ++i) {
        size_t tc = (size_t)T_TOK / cands[i];
        if (WPRE * 2 + tc * 3072 <= ws_size) { NC = cands[i]; break; }
    }
    const int TC = T_TOK / NC;
    const int BLC = BLROWS / NC;
    ushortT* xnC = wsu + WPRE;
    ushortT* big = xnC + (size_t)TC * 256;
    ushortT* oC  = big + (size_t)TC * 1024;

    wprep_kernel<<<576, 256, 0, stream>>>(qkv_w, proj_w, w1, w2, wsu);
    hipMemcpyAsync(h, x, (size_t)T_TOK * DMODEL * sizeof(float),
                   hipMemcpyDeviceToDevice, stream);

    dim3 blk(256);
    for (int d = 0; d < 6; ++d) {
        for (int c = 0; c < NC; ++c) {
            float* hc = h + (size_t)c * TC * DMODEL;
            ln_kernel<true><<<TC / 4, blk, 0, stream>>>(hc, xnC, ln1_s + d * 256, ln1_b + d * 256);
            gemm_bf16<0><<<dim3(6, TC / 128), blk, 0, stream>>>(
                xnC, wsu + (size_t)d * 196608, qkv_b + d * 768, nullptr, big, 256, 768);
            attn_kernel<<<dim3(BLC * 4, NSEQ / 128), 512, 0, stream>>>(
                big, rel_tab + (size_t)d * 1023 * 4, oC);
            gemm_bf16<2><<<dim3(2, TC / 128), blk, 0, stream>>>(
                oC, wsu + 1179648 + (size_t)d * 65536, proj_b + d * 256, hc, nullptr, 256, 256);
        }
        for (int c = 0; c < NC; ++c) {
            float* hc = h + (size_t)c * TC * DMODEL;
            ln_kernel<true><<<TC / 4, blk, 0, stream>>>(hc, xnC, ln2_s + d * 256, ln2_b + d * 256);
            gemm_bf16<1><<<dim3(8, TC / 128), blk, 0, stream>>>(
                xnC, wsu + 1572864 + (size_t)d * 262144, b1 + d * 1024, nullptr, big, 256, 1024);
            gemm_bf16<2><<<dim3(2, TC / 128), blk, 0, stream>>>(
                big, wsu + 3145728 + (size_t)d * 262144, b2 + d * 256, hc, nullptr, 1024, 256);
        }
    }
    ln_kernel<false><<<T_TOK / 4, blk, 0, stream>>>(h, h, lnf_s, lnf_b);
}